// Round 15
// baseline (54.237 us; speedup 1.0000x reference)
//
#include <hip/hip_runtime.h>
#include <hip/hip_bf16.h>

#define B 32
#define T 8192
#define H 128

typedef __attribute__((ext_vector_type(8)))  short short8_t;   // 8 bf16 = 4 VGPR
typedef __attribute__((ext_vector_type(16))) float f32x16;     // MFMA 32x32 acc

static __device__ __forceinline__ unsigned fbits(float x) { return __builtin_bit_cast(unsigned, x); }
static __device__ __forceinline__ float bfloat(unsigned u) { return __builtin_bit_cast(float, u); }

// split float4 -> 2 u32 of bf16-hi (truncated) + 2 u32 of bf16-lo (exact rem)
static __device__ __forceinline__ void pack4(const float4 f,
                                             unsigned& hi0, unsigned& hi1,
                                             unsigned& lo0, unsigned& lo1) {
    const unsigned u0 = fbits(f.x), u1 = fbits(f.y), u2 = fbits(f.z), u3 = fbits(f.w);
    const unsigned h0 = u0 & 0xffff0000u, h1 = u1 & 0xffff0000u;
    const unsigned h2 = u2 & 0xffff0000u, h3 = u3 & 0xffff0000u;
    const float r0 = f.x - bfloat(h0), r1 = f.y - bfloat(h1);
    const float r2 = f.z - bfloat(h2), r3 = f.w - bfloat(h3);
    hi0 = (u0 >> 16) | h1;                      hi1 = (u2 >> 16) | h3;
    lo0 = (fbits(r0) >> 16) | (fbits(r1) & 0xffff0000u);
    lo1 = (fbits(r2) >> 16) | (fbits(r3) & 0xffff0000u);
}

// ws layout: [0,16K) u fp32 ; [16K,80K) W2 hi|lo frags bf16
#define WPK_OFF  16384

// ---------------------------------------------------------------------------
// Kernel 1 (merged prep): blocks 0..31 -> u[b][h]; blocks 32..39 -> pack W2.
// ---------------------------------------------------------------------------
__global__ void k_prep(const float* __restrict__ hidden,
                       const float* __restrict__ W_attn,
                       const float* __restrict__ b_attn,
                       float* __restrict__ u,
                       unsigned short* __restrict__ wpk) {
    const int tid = threadIdx.x;
    if (blockIdx.x < 32) {
        const int b = blockIdx.x;
        __shared__ float hrow[H];
        if (tid < H) hrow[tid] = hidden[b * H + tid];
        __syncthreads();
        if (tid < H) {
            const float* w = W_attn + (size_t)tid * (2 * H);
            float acc = b_attn[tid];
#pragma unroll
            for (int k = 0; k < H; ++k) acc = fmaf(w[k], hrow[k], acc);
            u[b * H + tid] = acc;
        }
    } else {
        const int idx  = (blockIdx.x - 32) * 256 + tid;   // 0..2047
        const int s    = idx >> 8;
        const int m    = (idx >> 6) & 3;
        const int lane = idx & 63;
        const int h    = m * 32 + (lane & 31);
        const int k0   = s * 16 + (lane >> 5) * 8;
        const float* src = W_attn + (size_t)h * (2 * H) + H + k0;
        const int base = ((s * 4 + m) * 64 + lane) * 8;
#pragma unroll
        for (int e = 0; e < 8; ++e) {
            const float x = src[e];
            const unsigned ux = fbits(x);
            const unsigned hb = ux & 0xffff0000u;         // truncated bf16 hi
            const float r = x - bfloat(hb);               // exact remainder
            wpk[base + e]         = (unsigned short)(ux >> 16);
            wpk[16384 + base + e] = (unsigned short)(fbits(r) >> 16);
        }
    }
}

// ---------------------------------------------------------------------------
// Kernel 2: scores via MFMA — r14 structure at 2 BLOCKS/CU (4 waves/SIMD).
//
// r14 (42.9 us total, scores ~31) left ~0.6 us/round of barrier+straggler
// stall: at 1 block/CU every wave drains into the round barrier with nothing
// else schedulable. This round: grid 512 x 16 t (8 rounds/block), 66 KB LDS
// -> 2 co-resident blocks/CU fill each other's barrier stalls.
//
// VGPR diet to fit the 128-reg cap of launch_bounds(512,4):
//  - acc C-init = 0; u folded in epilogue (e = acc + u before relu —
//    identical numerics to C-init=u).
//  - uf/vv loaded per round via asm-obfuscated pointers (breaks loop
//    invariance so they are NOT hoisted into 32 persistent regs; u=16 KB,
//    v=512 B are L1-hot).
// Persistent: W2 frags 64 + acc 16 + stg 16 + addressing ~= 115.
// SPILL TRIPWIRE: if WRITE balloons >>fills, the cap re-triggered r3-style
// spilling -> revert to launch_bounds(512,2) + uf/vv in regs (r14).
//
// Hot loop per s-step: 2 x ds_read_b128 + 3 MFMA (pack done at stage time;
// each element packed ONCE — r14's win). Rotation swizzle as r9-r14.
// ---------------------------------------------------------------------------
__global__ __launch_bounds__(512, 4) void k_scores_mfma(
    const float* __restrict__ enc,                 // [T*B][H]
    const float* __restrict__ u,                   // [B][H]
    const float* __restrict__ v,                   // [H]
    const unsigned short* __restrict__ wpk,        // 64 KB frag-ordered hi|lo
    float* __restrict__ scores)                    // [B][T]
{
    __shared__ uint2 hb[2][2048];                  // hi planes, 2 x 16 KB
    __shared__ uint2 lb[2][2048];                  // lo planes, 2 x 16 KB
    __shared__ float cbuf[2][2][4][32];            // [parity][tsel][mtile][b]

    const int tid   = threadIdx.x;
    const int lane  = tid & 63;
    const int wid   = tid >> 6;     // 0..7
    const int tsel  = wid >> 2;     // 0..1 : which t of the tile
    const int mtile = wid & 3;      // 0..3 : 32-row h-tile
    const int l31   = lane & 31;
    const int kh    = lane >> 5;

    // staging role: 8 threads per tile-row, 4 float4 each
    const int srow = tid >> 3;      // tile row 0..63
    const int st8  = tid & 7;

    const int t0 = blockIdx.x * 16;             // 8 tiles x 2 t per block
    const float4* enc4 = (const float4*)enc;    // 32 x 16B units per row

    // ---- W2 fragments for this wave's mtile -> 64 VGPRs (persistent) ----
    short8_t w2hi[8], w2lo[8];
#pragma unroll
    for (int s = 0; s < 8; ++s) {
        const int fo = ((s * 4 + mtile) * 64 + lane) * 8;   // ushort idx
        w2hi[s] = *(const short8_t*)(wpk + fo);
        w2lo[s] = *(const short8_t*)(wpk + 16384 + fo);
    }

    // ---- prologue: tile 0 -> buf0; issue tile-1 loads ----
    float4 stg[4];
    {
        const float4* gs = enc4 + ((size_t)(t0 + 0) * 32 + srow) * 32;
#pragma unroll
        for (int i = 0; i < 4; ++i) stg[i] = gs[st8 + 8 * i];
#pragma unroll
        for (int i = 0; i < 4; ++i) {
            unsigned hi0, hi1, lo0, lo1;
            pack4(stg[i], hi0, hi1, lo0, lo1);
            const int p16 = st8 + 8 * i;
            const int idx = srow * 32 + (((p16 >> 1) + srow) & 15) * 2 + (p16 & 1);
            hb[0][idx] = make_uint2(hi0, hi1);
            lb[0][idx] = make_uint2(lo0, lo1);
        }
        const float4* gs1 = enc4 + ((size_t)(t0 + 2) * 32 + srow) * 32;
#pragma unroll
        for (int i = 0; i < 4; ++i) stg[i] = gs1[st8 + 8 * i];
    }
    __syncthreads();   // buf0 ready

    const int rrow  = tsel * 32 + l31;          // reader's tile row
    const int rbase = rrow * 32;                // uint2 base of that row

#pragma unroll 1
    for (int q = 0; q < 8; ++q) {
        const int cur = q & 1, nxt = cur ^ 1;

        // ---- pack+write tile q+1 (in stg) into buf[nxt] ----
        if (q < 7) {
#pragma unroll
            for (int i = 0; i < 4; ++i) {
                unsigned hi0, hi1, lo0, lo1;
                pack4(stg[i], hi0, hi1, lo0, lo1);
                const int p16 = st8 + 8 * i;
                const int idx = srow * 32 + (((p16 >> 1) + srow) & 15) * 2 + (p16 & 1);
                hb[nxt][idx] = make_uint2(hi0, hi1);
                lb[nxt][idx] = make_uint2(lo0, lo1);
            }
        }
        // ---- issue tile q+2 loads (latency hides under compute) ----
        if (q < 6) {
            const float4* gs = enc4 + ((size_t)(t0 + 2 * (q + 2)) * 32 + srow) * 32;
#pragma unroll
            for (int i = 0; i < 4; ++i) stg[i] = gs[st8 + 8 * i];
        }

        // ---- compute own (t, mtile) from buf[cur]: 2 ds_read + 3 MFMA /s ----
        f32x16 acc = {};   // C-init 0; u folded below (identical numerics)

#pragma unroll
        for (int s = 0; s < 8; ++s) {
            const int slot = (2 * s + kh + l31) & 15;       // (unit+row)&15
            const short8_t bh = *(const short8_t*)&hb[cur][rbase + slot * 2];
            const short8_t bl = *(const short8_t*)&lb[cur][rbase + slot * 2];
            acc = __builtin_amdgcn_mfma_f32_32x32x16_bf16(w2hi[s], bh, acc, 0, 0, 0);
            acc = __builtin_amdgcn_mfma_f32_32x32x16_bf16(w2lo[s], bh, acc, 0, 0, 0);
            acc = __builtin_amdgcn_mfma_f32_32x32x16_bf16(w2hi[s], bl, acc, 0, 0, 0);
        }

        // ---- epilogue: e = acc + u, relu, dot v (uf/vv loaded per round;
        //      asm breaks loop-invariance so they stay transient) ----
        const float* up = u;
        const float* vp = v;
        asm volatile("" : "+v"(up), "+v"(vp));

        float psum = 0.f;
#pragma unroll
        for (int r4 = 0; r4 < 4; ++r4) {
            const float4 ufr = *(const float4*)(up + l31 * H + mtile * 32 + r4 * 8 + kh * 4);
            const float4 vvr = *(const float4*)(vp + mtile * 32 + r4 * 8 + kh * 4);
            psum = fmaf(fmaxf(acc[4 * r4 + 0] + ufr.x, 0.f), vvr.x, psum);
            psum = fmaf(fmaxf(acc[4 * r4 + 1] + ufr.y, 0.f), vvr.y, psum);
            psum = fmaf(fmaxf(acc[4 * r4 + 2] + ufr.z, 0.f), vvr.z, psum);
            psum = fmaf(fmaxf(acc[4 * r4 + 3] + ufr.w, 0.f), vvr.w, psum);
        }
        psum += __shfl_xor(psum, 32);   // collapse kh halves; lanes<32 hold b

        if (lane < 32) cbuf[cur][tsel][mtile][l31] = psum;

        __syncthreads();   // buf[nxt] written, cbuf[cur] visible, buf[cur] free

        if (mtile == 0 && lane < 32) {
            const float r = cbuf[cur][tsel][0][l31] + cbuf[cur][tsel][1][l31]
                          + cbuf[cur][tsel][2][l31] + cbuf[cur][tsel][3][l31];
            scores[(size_t)l31 * T + (t0 + 2 * q + tsel)] = r;
        }
    }
}

// ---------------------------------------------------------------------------
// Kernel 3: ragged masked softmax per b, row in registers (1R + 1W).
// ---------------------------------------------------------------------------
#define SM_TPB 1024
#define SM_PER (T / SM_TPB)

__global__ __launch_bounds__(SM_TPB) void k_softmax(
    float* __restrict__ out, const int* __restrict__ len_seq)
{
    const int b    = blockIdx.x;
    const int tid  = threadIdx.x;
    const int lane = tid & 63;
    const int wid  = tid >> 6;
    const int len  = len_seq[b];
    float* s = out + (size_t)b * T;

    __shared__ float red[16];

    float val[SM_PER];
#pragma unroll
    for (int i = 0; i < SM_PER; ++i) val[i] = s[tid + i * SM_TPB];

    float m = -1e30f;
#pragma unroll
    for (int i = 0; i < SM_PER; ++i)
        if (tid + i * SM_TPB < len) m = fmaxf(m, val[i]);
#pragma unroll
    for (int off = 32; off >= 1; off >>= 1) m = fmaxf(m, __shfl_xor(m, off));
    if (lane == 0) red[wid] = m;
    __syncthreads();
    if (wid == 0) {
        float xv = (lane < 16) ? red[lane] : -1e30f;
#pragma unroll
        for (int off = 8; off >= 1; off >>= 1) xv = fmaxf(xv, __shfl_xor(xv, off));
        if (lane == 0) red[0] = xv;
    }
    __syncthreads();
    m = red[0];
    __syncthreads();

    float sum = 0.0f;
#pragma unroll
    for (int i = 0; i < SM_PER; ++i) {
        const int t = tid + i * SM_TPB;
        val[i] = (t < len) ? __expf(val[i] - m) : 0.0f;
        sum += val[i];
    }
#pragma unroll
    for (int off = 32; off >= 1; off >>= 1) sum += __shfl_xor(sum, off);
    if (lane == 0) red[wid] = sum;
    __syncthreads();
    if (wid == 0) {
        float xv = (lane < 16) ? red[lane] : 0.f;
#pragma unroll
        for (int off = 8; off >= 1; off >>= 1) xv += __shfl_xor(xv, off);
        if (lane == 0) red[0] = xv;
    }
    __syncthreads();
    const float inv = 1.0f / red[0];

#pragma unroll
    for (int i = 0; i < SM_PER; ++i) s[tid + i * SM_TPB] = val[i] * inv;
}

// ---------------------------------------------------------------------------
extern "C" void kernel_launch(void* const* d_in, const int* in_sizes, int n_in,
                              void* d_out, int out_size, void* d_ws, size_t ws_size,
                              hipStream_t stream) {
    const float* hidden = (const float*)d_in[0];
    const float* enc    = (const float*)d_in[1];
    const int*   len    = (const int*)d_in[2];
    const float* W      = (const float*)d_in[3];
    const float* bb     = (const float*)d_in[4];
    const float* v      = (const float*)d_in[5];

    float* out  = (float*)d_out;
    float* u_ws = (float*)d_ws;                                     // 16 KB
    unsigned short* wpk = (unsigned short*)((char*)d_ws + WPK_OFF); // 64 KB

    k_prep<<<40, 256, 0, stream>>>(hidden, W, bb, u_ws, wpk);
    k_scores_mfma<<<512, 512, 0, stream>>>(enc, u_ws, v, wpk, out);
    k_softmax<<<B, SM_TPB, 0, stream>>>(out, len);
}

// Round 16
// 42.616 us; speedup vs baseline: 1.2727x; 1.2727x over previous
//
#include <hip/hip_runtime.h>
#include <hip/hip_bf16.h>

#define B 32
#define T 8192
#define H 128

typedef __attribute__((ext_vector_type(8)))  short short8_t;   // 8 bf16 = 4 VGPR
typedef __attribute__((ext_vector_type(16))) float f32x16;     // MFMA 32x32 acc

static __device__ __forceinline__ unsigned fbits(float x) { return __builtin_bit_cast(unsigned, x); }
static __device__ __forceinline__ float bfloat(unsigned u) { return __builtin_bit_cast(float, u); }

// split float4 -> 2 u32 of bf16-hi (truncated) + 2 u32 of bf16-lo (exact rem)
static __device__ __forceinline__ void pack4(const float4 f,
                                             unsigned& hi0, unsigned& hi1,
                                             unsigned& lo0, unsigned& lo1) {
    const unsigned u0 = fbits(f.x), u1 = fbits(f.y), u2 = fbits(f.z), u3 = fbits(f.w);
    const unsigned h0 = u0 & 0xffff0000u, h1 = u1 & 0xffff0000u;
    const unsigned h2 = u2 & 0xffff0000u, h3 = u3 & 0xffff0000u;
    const float r0 = f.x - bfloat(h0), r1 = f.y - bfloat(h1);
    const float r2 = f.z - bfloat(h2), r3 = f.w - bfloat(h3);
    hi0 = (u0 >> 16) | h1;                      hi1 = (u2 >> 16) | h3;
    lo0 = (fbits(r0) >> 16) | (fbits(r1) & 0xffff0000u);
    lo1 = (fbits(r2) >> 16) | (fbits(r3) & 0xffff0000u);
}

// ws layout: [0,16K) u fp32 ; [16K,80K) W2 hi|lo frags bf16
#define WPK_OFF  16384

// ---------------------------------------------------------------------------
// Kernel 1 (merged prep): blocks 0..31 -> u[b][h]; blocks 32..39 -> pack W2.
// ---------------------------------------------------------------------------
__global__ void k_prep(const float* __restrict__ hidden,
                       const float* __restrict__ W_attn,
                       const float* __restrict__ b_attn,
                       float* __restrict__ u,
                       unsigned short* __restrict__ wpk) {
    const int tid = threadIdx.x;
    if (blockIdx.x < 32) {
        const int b = blockIdx.x;
        __shared__ float hrow[H];
        if (tid < H) hrow[tid] = hidden[b * H + tid];
        __syncthreads();
        if (tid < H) {
            const float* w = W_attn + (size_t)tid * (2 * H);
            float acc = b_attn[tid];
#pragma unroll
            for (int k = 0; k < H; ++k) acc = fmaf(w[k], hrow[k], acc);
            u[b * H + tid] = acc;
        }
    } else {
        const int idx  = (blockIdx.x - 32) * 256 + tid;   // 0..2047
        const int s    = idx >> 8;
        const int m    = (idx >> 6) & 3;
        const int lane = idx & 63;
        const int h    = m * 32 + (lane & 31);
        const int k0   = s * 16 + (lane >> 5) * 8;
        const float* src = W_attn + (size_t)h * (2 * H) + H + k0;
        const int base = ((s * 4 + m) * 64 + lane) * 8;
#pragma unroll
        for (int e = 0; e < 8; ++e) {
            const float x = src[e];
            const unsigned ux = fbits(x);
            const unsigned hb = ux & 0xffff0000u;         // truncated bf16 hi
            const float r = x - bfloat(hb);               // exact remainder
            wpk[base + e]         = (unsigned short)(ux >> 16);
            wpk[16384 + base + e] = (unsigned short)(fbits(r) >> 16);
        }
    }
}

// ---------------------------------------------------------------------------
// Kernel 2: scores via MFMA — enc PRE-PACKED to bf16 hi/lo AT STAGE TIME.
// EXACT round-14 body (best measured: 42.9 us total, no spill).
//
// Why this shape (evidence ledger):
//  - pre-pack at stage time: r14's +22% — the hot loop is 2 ds_read_b128 +
//    3 MFMA per s-step, zero pack VALU (r10-r13 packed 4x-redundantly in
//    the loop and all landed 53-56 us regardless of transport schedule).
//  - launch_bounds(512,2), W2-in-regs: r15 showed the (512,4)/128-reg
//    occupancy route regresses (epilogue reload chain + cap pressure).
//  - rotation swizzle on hi/lo planes: validated conflict-free r9-r14.
//  - transport: simple T14 reg-stage, one __syncthreads/round; counted-vmcnt
//    3-buf (r13), fat dbuf (r12), DMA dbuf (r11) were all neutral.
// Numerics identical to r7-r15 (same truncation split, same MFMA order).
// ---------------------------------------------------------------------------
__global__ __launch_bounds__(512, 2) void k_scores_mfma(
    const float* __restrict__ enc,                 // [T*B][H]
    const float* __restrict__ u,                   // [B][H]
    const float* __restrict__ v,                   // [H]
    const unsigned short* __restrict__ wpk,        // 64 KB frag-ordered hi|lo
    float* __restrict__ scores)                    // [B][T]
{
    __shared__ uint2 hb[2][2048];                  // hi planes, 2 x 16 KB
    __shared__ uint2 lb[2][2048];                  // lo planes, 2 x 16 KB
    __shared__ float cbuf[2][2][4][32];            // [parity][tsel][mtile][b]

    const int tid   = threadIdx.x;
    const int lane  = tid & 63;
    const int wid   = tid >> 6;     // 0..7
    const int tsel  = wid >> 2;     // 0..1 : which t of the tile
    const int mtile = wid & 3;      // 0..3 : 32-row h-tile
    const int l31   = lane & 31;
    const int kh    = lane >> 5;

    // staging role: 8 threads per tile-row, 4 float4 each
    const int srow = tid >> 3;      // tile row 0..63
    const int st8  = tid & 7;

    const int t0 = blockIdx.x * 32;             // 16 tiles x 2 t per block
    const float4* enc4 = (const float4*)enc;    // 32 x 16B units per row

    // ---- W2 fragments for this wave's mtile -> 64 VGPRs ----
    short8_t w2hi[8], w2lo[8];
#pragma unroll
    for (int s = 0; s < 8; ++s) {
        const int fo = ((s * 4 + mtile) * 64 + lane) * 8;   // ushort idx
        w2hi[s] = *(const short8_t*)(wpk + fo);
        w2lo[s] = *(const short8_t*)(wpk + 16384 + fo);
    }
    float4 uf[4], vv[4];
#pragma unroll
    for (int r4 = 0; r4 < 4; ++r4) {
        uf[r4] = *(const float4*)(u + l31 * H + mtile * 32 + r4 * 8 + kh * 4);
        vv[r4] = *(const float4*)(v + mtile * 32 + r4 * 8 + kh * 4);
    }

    // ---- prologue: tile 0 -> buf0; issue tile-1 loads ----
    float4 stg[4];
    {
        const float4* gs = enc4 + ((size_t)(t0 + 0) * 32 + srow) * 32;
#pragma unroll
        for (int i = 0; i < 4; ++i) stg[i] = gs[st8 + 8 * i];
#pragma unroll
        for (int i = 0; i < 4; ++i) {
            unsigned hi0, hi1, lo0, lo1;
            pack4(stg[i], hi0, hi1, lo0, lo1);
            const int p16 = st8 + 8 * i;
            const int idx = srow * 32 + (((p16 >> 1) + srow) & 15) * 2 + (p16 & 1);
            hb[0][idx] = make_uint2(hi0, hi1);
            lb[0][idx] = make_uint2(lo0, lo1);
        }
        const float4* gs1 = enc4 + ((size_t)(t0 + 2) * 32 + srow) * 32;
#pragma unroll
        for (int i = 0; i < 4; ++i) stg[i] = gs1[st8 + 8 * i];
    }
    __syncthreads();   // buf0 ready

    const int rrow  = tsel * 32 + l31;          // reader's tile row
    const int rbase = rrow * 32;                // uint2 base of that row

#pragma unroll 1
    for (int q = 0; q < 16; ++q) {
        const int cur = q & 1, nxt = cur ^ 1;

        // ---- pack+write tile q+1 (in stg) into buf[nxt] ----
        if (q < 15) {
#pragma unroll
            for (int i = 0; i < 4; ++i) {
                unsigned hi0, hi1, lo0, lo1;
                pack4(stg[i], hi0, hi1, lo0, lo1);
                const int p16 = st8 + 8 * i;
                const int idx = srow * 32 + (((p16 >> 1) + srow) & 15) * 2 + (p16 & 1);
                hb[nxt][idx] = make_uint2(hi0, hi1);
                lb[nxt][idx] = make_uint2(lo0, lo1);
            }
        }
        // ---- issue tile q+2 loads (latency hides under compute) ----
        if (q < 14) {
            const float4* gs = enc4 + ((size_t)(t0 + 2 * (q + 2)) * 32 + srow) * 32;
#pragma unroll
            for (int i = 0; i < 4; ++i) stg[i] = gs[st8 + 8 * i];
        }

        // ---- compute own (t, mtile) from buf[cur]: 2 ds_read + 3 MFMA /s ----
        f32x16 acc;
#pragma unroll
        for (int r4 = 0; r4 < 4; ++r4) {
            acc[4 * r4 + 0] = uf[r4].x; acc[4 * r4 + 1] = uf[r4].y;
            acc[4 * r4 + 2] = uf[r4].z; acc[4 * r4 + 3] = uf[r4].w;
        }

#pragma unroll
        for (int s = 0; s < 8; ++s) {
            const int slot = (2 * s + kh + l31) & 15;       // (unit+row)&15
            const short8_t bh = *(const short8_t*)&hb[cur][rbase + slot * 2];
            const short8_t bl = *(const short8_t*)&lb[cur][rbase + slot * 2];
            acc = __builtin_amdgcn_mfma_f32_32x32x16_bf16(w2hi[s], bh, acc, 0, 0, 0);
            acc = __builtin_amdgcn_mfma_f32_32x32x16_bf16(w2lo[s], bh, acc, 0, 0, 0);
            acc = __builtin_amdgcn_mfma_f32_32x32x16_bf16(w2hi[s], bl, acc, 0, 0, 0);
        }

        // ---- partial score over this wave's 32 h-rows ----
        float psum = 0.f;
#pragma unroll
        for (int r4 = 0; r4 < 4; ++r4) {
            psum = fmaf(fmaxf(acc[4 * r4 + 0], 0.f), vv[r4].x, psum);
            psum = fmaf(fmaxf(acc[4 * r4 + 1], 0.f), vv[r4].y, psum);
            psum = fmaf(fmaxf(acc[4 * r4 + 2], 0.f), vv[r4].z, psum);
            psum = fmaf(fmaxf(acc[4 * r4 + 3], 0.f), vv[r4].w, psum);
        }
        psum += __shfl_xor(psum, 32);   // collapse kh halves; lanes<32 hold b

        if (lane < 32) cbuf[cur][tsel][mtile][l31] = psum;

        __syncthreads();   // buf[nxt] written, cbuf[cur] visible, buf[cur] free

        if (mtile == 0 && lane < 32) {
            const float r = cbuf[cur][tsel][0][l31] + cbuf[cur][tsel][1][l31]
                          + cbuf[cur][tsel][2][l31] + cbuf[cur][tsel][3][l31];
            scores[(size_t)l31 * T + (t0 + 2 * q + tsel)] = r;
        }
    }
}

// ---------------------------------------------------------------------------
// Kernel 3: ragged masked softmax per b, row in registers (1R + 1W).
// ---------------------------------------------------------------------------
#define SM_TPB 1024
#define SM_PER (T / SM_TPB)

__global__ __launch_bounds__(SM_TPB) void k_softmax(
    float* __restrict__ out, const int* __restrict__ len_seq)
{
    const int b    = blockIdx.x;
    const int tid  = threadIdx.x;
    const int lane = tid & 63;
    const int wid  = tid >> 6;
    const int len  = len_seq[b];
    float* s = out + (size_t)b * T;

    __shared__ float red[16];

    float val[SM_PER];
#pragma unroll
    for (int i = 0; i < SM_PER; ++i) val[i] = s[tid + i * SM_TPB];

    float m = -1e30f;
#pragma unroll
    for (int i = 0; i < SM_PER; ++i)
        if (tid + i * SM_TPB < len) m = fmaxf(m, val[i]);
#pragma unroll
    for (int off = 32; off >= 1; off >>= 1) m = fmaxf(m, __shfl_xor(m, off));
    if (lane == 0) red[wid] = m;
    __syncthreads();
    if (wid == 0) {
        float xv = (lane < 16) ? red[lane] : -1e30f;
#pragma unroll
        for (int off = 8; off >= 1; off >>= 1) xv = fmaxf(xv, __shfl_xor(xv, off));
        if (lane == 0) red[0] = xv;
    }
    __syncthreads();
    m = red[0];
    __syncthreads();

    float sum = 0.0f;
#pragma unroll
    for (int i = 0; i < SM_PER; ++i) {
        const int t = tid + i * SM_TPB;
        val[i] = (t < len) ? __expf(val[i] - m) : 0.0f;
        sum += val[i];
    }
#pragma unroll
    for (int off = 32; off >= 1; off >>= 1) sum += __shfl_xor(sum, off);
    if (lane == 0) red[wid] = sum;
    __syncthreads();
    if (wid == 0) {
        float xv = (lane < 16) ? red[lane] : 0.f;
#pragma unroll
        for (int off = 8; off >= 1; off >>= 1) xv += __shfl_xor(xv, off);
        if (lane == 0) red[0] = xv;
    }
    __syncthreads();
    const float inv = 1.0f / red[0];

#pragma unroll
    for (int i = 0; i < SM_PER; ++i) s[tid + i * SM_TPB] = val[i] * inv;
}

// ---------------------------------------------------------------------------
extern "C" void kernel_launch(void* const* d_in, const int* in_sizes, int n_in,
                              void* d_out, int out_size, void* d_ws, size_t ws_size,
                              hipStream_t stream) {
    const float* hidden = (const float*)d_in[0];
    const float* enc    = (const float*)d_in[1];
    const int*   len    = (const int*)d_in[2];
    const float* W      = (const float*)d_in[3];
    const float* bb     = (const float*)d_in[4];
    const float* v      = (const float*)d_in[5];

    float* out  = (float*)d_out;
    float* u_ws = (float*)d_ws;                                     // 16 KB
    unsigned short* wpk = (unsigned short*)((char*)d_ws + WPK_OFF); // 64 KB

    k_prep<<<40, 256, 0, stream>>>(hidden, W, bb, u_ws, wpk);
    k_scores_mfma<<<256, 512, 0, stream>>>(enc, u_ws, v, wpk, out);
    k_softmax<<<B, SM_TPB, 0, stream>>>(out, len);
}

// Round 17
// 36.064 us; speedup vs baseline: 1.5039x; 1.1817x over previous
//
#include <hip/hip_runtime.h>
#include <hip/hip_bf16.h>

#define B 32
#define T 8192
#define H 128

typedef __attribute__((ext_vector_type(8)))  short short8_t;   // 8 bf16 = 4 VGPR
typedef __attribute__((ext_vector_type(16))) float f32x16;     // MFMA 32x32 acc

static __device__ __forceinline__ unsigned fbits(float x) { return __builtin_bit_cast(unsigned, x); }
static __device__ __forceinline__ float bfloat(unsigned u) { return __builtin_bit_cast(float, u); }

// pack float4 -> 2 u32 of bf16-hi (truncated). x-lo is DROPPED (see kernel 2
// header: precision budget traded for LDS bandwidth; W-lo term retained).
static __device__ __forceinline__ void pack4hi(const float4 f,
                                               unsigned& hi0, unsigned& hi1) {
    const unsigned u0 = fbits(f.x), u1 = fbits(f.y), u2 = fbits(f.z), u3 = fbits(f.w);
    hi0 = (u0 >> 16) | (u1 & 0xffff0000u);
    hi1 = (u2 >> 16) | (u3 & 0xffff0000u);
}

// ws layout: [0,16K) u fp32 ; [16K,80K) W2 hi|lo frags bf16
#define WPK_OFF  16384

// ---------------------------------------------------------------------------
// Kernel 1 (merged prep): blocks 0..31 -> u[b][h]; blocks 32..39 -> pack W2.
// ---------------------------------------------------------------------------
__global__ void k_prep(const float* __restrict__ hidden,
                       const float* __restrict__ W_attn,
                       const float* __restrict__ b_attn,
                       float* __restrict__ u,
                       unsigned short* __restrict__ wpk) {
    const int tid = threadIdx.x;
    if (blockIdx.x < 32) {
        const int b = blockIdx.x;
        __shared__ float hrow[H];
        if (tid < H) hrow[tid] = hidden[b * H + tid];
        __syncthreads();
        if (tid < H) {
            const float* w = W_attn + (size_t)tid * (2 * H);
            float acc = b_attn[tid];
#pragma unroll
            for (int k = 0; k < H; ++k) acc = fmaf(w[k], hrow[k], acc);
            u[b * H + tid] = acc;
        }
    } else {
        const int idx  = (blockIdx.x - 32) * 256 + tid;   // 0..2047
        const int s    = idx >> 8;
        const int m    = (idx >> 6) & 3;
        const int lane = idx & 63;
        const int h    = m * 32 + (lane & 31);
        const int k0   = s * 16 + (lane >> 5) * 8;
        const float* src = W_attn + (size_t)h * (2 * H) + H + k0;
        const int base = ((s * 4 + m) * 64 + lane) * 8;
#pragma unroll
        for (int e = 0; e < 8; ++e) {
            const float x = src[e];
            const unsigned ux = fbits(x);
            const unsigned hb = ux & 0xffff0000u;         // truncated bf16 hi
            const float r = x - bfloat(hb);               // exact remainder
            wpk[base + e]         = (unsigned short)(ux >> 16);
            wpk[16384 + base + e] = (unsigned short)(fbits(r) >> 16);
        }
    }
}

// ---------------------------------------------------------------------------
// Kernel 2: scores via MFMA — 2-TERM hi/lo: E ~= Whi.Xhi + Wlo.Xhi.
//
// r14/r16 (42.6-42.9 us) was LDS-pipe co-bound: 256 ds_read_b128 + 256
// ds_write_b64 per CU per round ~ 1.6 us vs HBM leg 1.3 us. The 4x B-frag
// read redundancy is locked in by the W2-in-regs 4-way m-split (2-way
// split doesn't fit registers: r9/r15). This round spends PRECISION margin
// instead: drop the Xlo term (Whi.Xlo). Error analysis: rms(xlo) ~ 2^-8/sqrt3
// relative -> energy err ~1.3e-3 -> prob absmax ~3e-5, vs threshold 1.5e-4
// (measured r16 absmax was 1.5e-5 with 10x headroom). W-lo term kept, W2
// packed hi+lo in regs as before.
// Payoff: x-lo plane gone -> LDS reads 2->1 b128 per s-step (64/CU/round),
// writes halve, pack VALU halves, LDS 66->34 KB. LDS leg ~0.5 us/round,
// decisively under the HBM leg -> round wall = HBM stage share.
//
// Everything else identical to r16: transport = T14 reg-stage double-buffer
// (one __syncthreads/round), rotation swizzle (validated r9-r16),
// launch_bounds(512,2) + W2-in-regs (r15 showed (512,4) regresses).
// ---------------------------------------------------------------------------
__global__ __launch_bounds__(512, 2) void k_scores_mfma(
    const float* __restrict__ enc,                 // [T*B][H]
    const float* __restrict__ u,                   // [B][H]
    const float* __restrict__ v,                   // [H]
    const unsigned short* __restrict__ wpk,        // 64 KB frag-ordered hi|lo
    float* __restrict__ scores)                    // [B][T]
{
    __shared__ uint2 hb[2][2048];                  // hi planes, 2 x 16 KB
    __shared__ float cbuf[2][2][4][32];            // [parity][tsel][mtile][b]

    const int tid   = threadIdx.x;
    const int lane  = tid & 63;
    const int wid   = tid >> 6;     // 0..7
    const int tsel  = wid >> 2;     // 0..1 : which t of the tile
    const int mtile = wid & 3;      // 0..3 : 32-row h-tile
    const int l31   = lane & 31;
    const int kh    = lane >> 5;

    // staging role: 8 threads per tile-row, 4 float4 each
    const int srow = tid >> 3;      // tile row 0..63
    const int st8  = tid & 7;

    const int t0 = blockIdx.x * 32;             // 16 tiles x 2 t per block
    const float4* enc4 = (const float4*)enc;    // 32 x 16B units per row

    // ---- W2 fragments for this wave's mtile -> 64 VGPRs ----
    short8_t w2hi[8], w2lo[8];
#pragma unroll
    for (int s = 0; s < 8; ++s) {
        const int fo = ((s * 4 + mtile) * 64 + lane) * 8;   // ushort idx
        w2hi[s] = *(const short8_t*)(wpk + fo);
        w2lo[s] = *(const short8_t*)(wpk + 16384 + fo);
    }
    float4 uf[4], vv[4];
#pragma unroll
    for (int r4 = 0; r4 < 4; ++r4) {
        uf[r4] = *(const float4*)(u + l31 * H + mtile * 32 + r4 * 8 + kh * 4);
        vv[r4] = *(const float4*)(v + mtile * 32 + r4 * 8 + kh * 4);
    }

    // ---- prologue: tile 0 -> buf0; issue tile-1 loads ----
    float4 stg[4];
    {
        const float4* gs = enc4 + ((size_t)(t0 + 0) * 32 + srow) * 32;
#pragma unroll
        for (int i = 0; i < 4; ++i) stg[i] = gs[st8 + 8 * i];
#pragma unroll
        for (int i = 0; i < 4; ++i) {
            unsigned hi0, hi1;
            pack4hi(stg[i], hi0, hi1);
            const int p16 = st8 + 8 * i;
            const int idx = srow * 32 + (((p16 >> 1) + srow) & 15) * 2 + (p16 & 1);
            hb[0][idx] = make_uint2(hi0, hi1);
        }
        const float4* gs1 = enc4 + ((size_t)(t0 + 2) * 32 + srow) * 32;
#pragma unroll
        for (int i = 0; i < 4; ++i) stg[i] = gs1[st8 + 8 * i];
    }
    __syncthreads();   // buf0 ready

    const int rrow  = tsel * 32 + l31;          // reader's tile row
    const int rbase = rrow * 32;                // uint2 base of that row

#pragma unroll 1
    for (int q = 0; q < 16; ++q) {
        const int cur = q & 1, nxt = cur ^ 1;

        // ---- pack+write tile q+1 (in stg) into buf[nxt] ----
        if (q < 15) {
#pragma unroll
            for (int i = 0; i < 4; ++i) {
                unsigned hi0, hi1;
                pack4hi(stg[i], hi0, hi1);
                const int p16 = st8 + 8 * i;
                const int idx = srow * 32 + (((p16 >> 1) + srow) & 15) * 2 + (p16 & 1);
                hb[nxt][idx] = make_uint2(hi0, hi1);
            }
        }
        // ---- issue tile q+2 loads (latency hides under compute) ----
        if (q < 14) {
            const float4* gs = enc4 + ((size_t)(t0 + 2 * (q + 2)) * 32 + srow) * 32;
#pragma unroll
            for (int i = 0; i < 4; ++i) stg[i] = gs[st8 + 8 * i];
        }

        // ---- compute own (t, mtile) from buf[cur]: 1 ds_read + 2 MFMA /s ----
        f32x16 acc;
#pragma unroll
        for (int r4 = 0; r4 < 4; ++r4) {
            acc[4 * r4 + 0] = uf[r4].x; acc[4 * r4 + 1] = uf[r4].y;
            acc[4 * r4 + 2] = uf[r4].z; acc[4 * r4 + 3] = uf[r4].w;
        }

#pragma unroll
        for (int s = 0; s < 8; ++s) {
            const int slot = (2 * s + kh + l31) & 15;       // (unit+row)&15
            const short8_t bh = *(const short8_t*)&hb[cur][rbase + slot * 2];
            acc = __builtin_amdgcn_mfma_f32_32x32x16_bf16(w2hi[s], bh, acc, 0, 0, 0);
            acc = __builtin_amdgcn_mfma_f32_32x32x16_bf16(w2lo[s], bh, acc, 0, 0, 0);
        }

        // ---- partial score over this wave's 32 h-rows ----
        float psum = 0.f;
#pragma unroll
        for (int r4 = 0; r4 < 4; ++r4) {
            psum = fmaf(fmaxf(acc[4 * r4 + 0], 0.f), vv[r4].x, psum);
            psum = fmaf(fmaxf(acc[4 * r4 + 1], 0.f), vv[r4].y, psum);
            psum = fmaf(fmaxf(acc[4 * r4 + 2], 0.f), vv[r4].z, psum);
            psum = fmaf(fmaxf(acc[4 * r4 + 3], 0.f), vv[r4].w, psum);
        }
        psum += __shfl_xor(psum, 32);   // collapse kh halves; lanes<32 hold b

        if (lane < 32) cbuf[cur][tsel][mtile][l31] = psum;

        __syncthreads();   // buf[nxt] written, cbuf[cur] visible, buf[cur] free

        if (mtile == 0 && lane < 32) {
            const float r = cbuf[cur][tsel][0][l31] + cbuf[cur][tsel][1][l31]
                          + cbuf[cur][tsel][2][l31] + cbuf[cur][tsel][3][l31];
            scores[(size_t)l31 * T + (t0 + 2 * q + tsel)] = r;
        }
    }
}

// ---------------------------------------------------------------------------
// Kernel 3: ragged masked softmax per b, row in registers (1R + 1W).
// ---------------------------------------------------------------------------
#define SM_TPB 1024
#define SM_PER (T / SM_TPB)

__global__ __launch_bounds__(SM_TPB) void k_softmax(
    float* __restrict__ out, const int* __restrict__ len_seq)
{
    const int b    = blockIdx.x;
    const int tid  = threadIdx.x;
    const int lane = tid & 63;
    const int wid  = tid >> 6;
    const int len  = len_seq[b];
    float* s = out + (size_t)b * T;

    __shared__ float red[16];

    float val[SM_PER];
#pragma unroll
    for (int i = 0; i < SM_PER; ++i) val[i] = s[tid + i * SM_TPB];

    float m = -1e30f;
#pragma unroll
    for (int i = 0; i < SM_PER; ++i)
        if (tid + i * SM_TPB < len) m = fmaxf(m, val[i]);
#pragma unroll
    for (int off = 32; off >= 1; off >>= 1) m = fmaxf(m, __shfl_xor(m, off));
    if (lane == 0) red[wid] = m;
    __syncthreads();
    if (wid == 0) {
        float xv = (lane < 16) ? red[lane] : -1e30f;
#pragma unroll
        for (int off = 8; off >= 1; off >>= 1) xv = fmaxf(xv, __shfl_xor(xv, off));
        if (lane == 0) red[0] = xv;
    }
    __syncthreads();
    m = red[0];
    __syncthreads();

    float sum = 0.0f;
#pragma unroll
    for (int i = 0; i < SM_PER; ++i) {
        const int t = tid + i * SM_TPB;
        val[i] = (t < len) ? __expf(val[i] - m) : 0.0f;
        sum += val[i];
    }
#pragma unroll
    for (int off = 32; off >= 1; off >>= 1) sum += __shfl_xor(sum, off);
    if (lane == 0) red[wid] = sum;
    __syncthreads();
    if (wid == 0) {
        float xv = (lane < 16) ? red[lane] : 0.f;
#pragma unroll
        for (int off = 8; off >= 1; off >>= 1) xv += __shfl_xor(xv, off);
        if (lane == 0) red[0] = xv;
    }
    __syncthreads();
    const float inv = 1.0f / red[0];

#pragma unroll
    for (int i = 0; i < SM_PER; ++i) s[tid + i * SM_TPB] = val[i] * inv;
}

// ---------------------------------------------------------------------------
extern "C" void kernel_launch(void* const* d_in, const int* in_sizes, int n_in,
                              void* d_out, int out_size, void* d_ws, size_t ws_size,
                              hipStream_t stream) {
    const float* hidden = (const float*)d_in[0];
    const float* enc    = (const float*)d_in[1];
    const int*   len    = (const int*)d_in[2];
    const float* W      = (const float*)d_in[3];
    const float* bb     = (const float*)d_in[4];
    const float* v      = (const float*)d_in[5];

    float* out  = (float*)d_out;
    float* u_ws = (float*)d_ws;                                     // 16 KB
    unsigned short* wpk = (unsigned short*)((char*)d_ws + WPK_OFF); // 64 KB

    k_prep<<<40, 256, 0, stream>>>(hidden, W, bb, u_ws, wpk);
    k_scores_mfma<<<256, 512, 0, stream>>>(enc, u_ws, v, wpk, out);
    k_softmax<<<B, SM_TPB, 0, stream>>>(out, len);
}

// Round 18
// 35.953 us; speedup vs baseline: 1.5085x; 1.0031x over previous
//
#include <hip/hip_runtime.h>
#include <hip/hip_bf16.h>

#define B 32
#define T 8192
#define H 128

typedef __attribute__((ext_vector_type(8)))  short short8_t;   // 8 bf16 = 4 VGPR
typedef __attribute__((ext_vector_type(16))) float f32x16;     // MFMA 32x32 acc

static __device__ __forceinline__ unsigned fbits(float x) { return __builtin_bit_cast(unsigned, x); }
static __device__ __forceinline__ float bfloat(unsigned u) { return __builtin_bit_cast(float, u); }

// pack float4 -> 2 u32 of bf16-hi (truncated). x-lo DROPPED (r17: precision
// budget -> LDS bandwidth; absmax 3.05e-5 vs 1.495e-4 threshold).
static __device__ __forceinline__ void pack4hi(const float4 f,
                                               unsigned& hi0, unsigned& hi1) {
    const unsigned u0 = fbits(f.x), u1 = fbits(f.y), u2 = fbits(f.z), u3 = fbits(f.w);
    hi0 = (u0 >> 16) | (u1 & 0xffff0000u);
    hi1 = (u2 >> 16) | (u3 & 0xffff0000u);
}

// ws layout: [0,16K) u fp32 ; [16K,80K) W2 hi|lo frags ; [80K,144K) sm partials
// (ws_size ~512 MiB per harness fill counters — ample)
#define WPK_OFF  16384
#define PART_OFF 81920

// ---------------------------------------------------------------------------
// Kernel 1 (merged prep): blocks 0..31 -> u[b][h]; blocks 32..39 -> pack W2.
// ---------------------------------------------------------------------------
__global__ void k_prep(const float* __restrict__ hidden,
                       const float* __restrict__ W_attn,
                       const float* __restrict__ b_attn,
                       float* __restrict__ u,
                       unsigned short* __restrict__ wpk) {
    const int tid = threadIdx.x;
    if (blockIdx.x < 32) {
        const int b = blockIdx.x;
        __shared__ float hrow[H];
        if (tid < H) hrow[tid] = hidden[b * H + tid];
        __syncthreads();
        if (tid < H) {
            const float* w = W_attn + (size_t)tid * (2 * H);
            float acc = b_attn[tid];
#pragma unroll
            for (int k = 0; k < H; ++k) acc = fmaf(w[k], hrow[k], acc);
            u[b * H + tid] = acc;
        }
    } else {
        const int idx  = (blockIdx.x - 32) * 256 + tid;   // 0..2047
        const int s    = idx >> 8;
        const int m    = (idx >> 6) & 3;
        const int lane = idx & 63;
        const int h    = m * 32 + (lane & 31);
        const int k0   = s * 16 + (lane >> 5) * 8;
        const float* src = W_attn + (size_t)h * (2 * H) + H + k0;
        const int base = ((s * 4 + m) * 64 + lane) * 8;
#pragma unroll
        for (int e = 0; e < 8; ++e) {
            const float x = src[e];
            const unsigned ux = fbits(x);
            const unsigned hb = ux & 0xffff0000u;         // truncated bf16 hi
            const float r = x - bfloat(hb);               // exact remainder
            wpk[base + e]         = (unsigned short)(ux >> 16);
            wpk[16384 + base + e] = (unsigned short)(fbits(r) >> 16);
        }
    }
}

// ---------------------------------------------------------------------------
// Kernel 2: scores via MFMA — r17 body (36.1 us total) + FUSED softmax
// partials: the flush threads additionally keep an online (max, exp-sum)
// over their block's 16 valid scores per b and write one (M,S) per (b,blk)
// at the end. Enables a 256-block softmax without an extra launch (r8's
// 2-phase split was neutral because its extra launch gap ate the gain).
//
// Evidence ledger (unchanged parts):
//  - pre-pack at stage time (r14 +22%), x-lo dropped (r17 +15%):
//    hot loop = 1 ds_read_b128 + 2 MFMA per s-step.
//  - launch_bounds(512,2), W2-in-regs (r15: the (512,4) route regresses).
//  - rotation swizzle validated r9-r17; T14 reg-stage double buffer
//    (counted-vmcnt r13 / fat dbuf r12 / DMA dbuf r11 all neutral).
// ---------------------------------------------------------------------------
__global__ __launch_bounds__(512, 2) void k_scores_mfma(
    const float* __restrict__ enc,                 // [T*B][H]
    const float* __restrict__ u,                   // [B][H]
    const float* __restrict__ v,                   // [H]
    const unsigned short* __restrict__ wpk,        // 64 KB frag-ordered hi|lo
    const int* __restrict__ len_seq,               // [B]
    float* __restrict__ scores,                    // [B][T]
    float* __restrict__ part)                      // [B][256] x (M,S)
{
    __shared__ uint2 hb[2][2048];                  // hi planes, 2 x 16 KB
    __shared__ float cbuf[2][2][4][32];            // [parity][tsel][mtile][b]
    __shared__ float pm[2][32], ps[2][32];         // partial fold buffers

    const int tid   = threadIdx.x;
    const int lane  = tid & 63;
    const int wid   = tid >> 6;     // 0..7
    const int tsel  = wid >> 2;     // 0..1 : which t of the tile
    const int mtile = wid & 3;      // 0..3 : 32-row h-tile
    const int l31   = lane & 31;
    const int kh    = lane >> 5;

    // staging role: 8 threads per tile-row, 4 float4 each
    const int srow = tid >> 3;      // tile row 0..63
    const int st8  = tid & 7;

    const int t0 = blockIdx.x * 32;             // 16 tiles x 2 t per block
    const float4* enc4 = (const float4*)enc;    // 32 x 16B units per row

    // ---- W2 fragments for this wave's mtile -> 64 VGPRs ----
    short8_t w2hi[8], w2lo[8];
#pragma unroll
    for (int s = 0; s < 8; ++s) {
        const int fo = ((s * 4 + mtile) * 64 + lane) * 8;   // ushort idx
        w2hi[s] = *(const short8_t*)(wpk + fo);
        w2lo[s] = *(const short8_t*)(wpk + 16384 + fo);
    }
    float4 uf[4], vv[4];
#pragma unroll
    for (int r4 = 0; r4 < 4; ++r4) {
        uf[r4] = *(const float4*)(u + l31 * H + mtile * 32 + r4 * 8 + kh * 4);
        vv[r4] = *(const float4*)(v + mtile * 32 + r4 * 8 + kh * 4);
    }
    const int lenb = len_seq[l31];              // only used by flush threads

    // ---- prologue: tile 0 -> buf0; issue tile-1 loads ----
    float4 stg[4];
    {
        const float4* gs = enc4 + ((size_t)(t0 + 0) * 32 + srow) * 32;
#pragma unroll
        for (int i = 0; i < 4; ++i) stg[i] = gs[st8 + 8 * i];
#pragma unroll
        for (int i = 0; i < 4; ++i) {
            unsigned hi0, hi1;
            pack4hi(stg[i], hi0, hi1);
            const int p16 = st8 + 8 * i;
            const int idx = srow * 32 + (((p16 >> 1) + srow) & 15) * 2 + (p16 & 1);
            hb[0][idx] = make_uint2(hi0, hi1);
        }
        const float4* gs1 = enc4 + ((size_t)(t0 + 2) * 32 + srow) * 32;
#pragma unroll
        for (int i = 0; i < 4; ++i) stg[i] = gs1[st8 + 8 * i];
    }
    __syncthreads();   // buf0 ready

    const int rrow  = tsel * 32 + l31;          // reader's tile row
    const int rbase = rrow * 32;                // uint2 base of that row

    float m_run = -1e30f, s_run = 0.0f;         // online softmax partial

#pragma unroll 1
    for (int q = 0; q < 16; ++q) {
        const int cur = q & 1, nxt = cur ^ 1;

        // ---- pack+write tile q+1 (in stg) into buf[nxt] ----
        if (q < 15) {
#pragma unroll
            for (int i = 0; i < 4; ++i) {
                unsigned hi0, hi1;
                pack4hi(stg[i], hi0, hi1);
                const int p16 = st8 + 8 * i;
                const int idx = srow * 32 + (((p16 >> 1) + srow) & 15) * 2 + (p16 & 1);
                hb[nxt][idx] = make_uint2(hi0, hi1);
            }
        }
        // ---- issue tile q+2 loads (latency hides under compute) ----
        if (q < 14) {
            const float4* gs = enc4 + ((size_t)(t0 + 2 * (q + 2)) * 32 + srow) * 32;
#pragma unroll
            for (int i = 0; i < 4; ++i) stg[i] = gs[st8 + 8 * i];
        }

        // ---- compute own (t, mtile) from buf[cur]: 1 ds_read + 2 MFMA /s ----
        f32x16 acc;
#pragma unroll
        for (int r4 = 0; r4 < 4; ++r4) {
            acc[4 * r4 + 0] = uf[r4].x; acc[4 * r4 + 1] = uf[r4].y;
            acc[4 * r4 + 2] = uf[r4].z; acc[4 * r4 + 3] = uf[r4].w;
        }

#pragma unroll
        for (int s = 0; s < 8; ++s) {
            const int slot = (2 * s + kh + l31) & 15;       // (unit+row)&15
            const short8_t bh = *(const short8_t*)&hb[cur][rbase + slot * 2];
            acc = __builtin_amdgcn_mfma_f32_32x32x16_bf16(w2hi[s], bh, acc, 0, 0, 0);
            acc = __builtin_amdgcn_mfma_f32_32x32x16_bf16(w2lo[s], bh, acc, 0, 0, 0);
        }

        // ---- partial score over this wave's 32 h-rows ----
        float psum = 0.f;
#pragma unroll
        for (int r4 = 0; r4 < 4; ++r4) {
            psum = fmaf(fmaxf(acc[4 * r4 + 0], 0.f), vv[r4].x, psum);
            psum = fmaf(fmaxf(acc[4 * r4 + 1], 0.f), vv[r4].y, psum);
            psum = fmaf(fmaxf(acc[4 * r4 + 2], 0.f), vv[r4].z, psum);
            psum = fmaf(fmaxf(acc[4 * r4 + 3], 0.f), vv[r4].w, psum);
        }
        psum += __shfl_xor(psum, 32);   // collapse kh halves; lanes<32 hold b

        if (lane < 32) cbuf[cur][tsel][mtile][l31] = psum;

        __syncthreads();   // buf[nxt] written, cbuf[cur] visible, buf[cur] free

        if (mtile == 0 && lane < 32) {
            const float r = cbuf[cur][tsel][0][l31] + cbuf[cur][tsel][1][l31]
                          + cbuf[cur][tsel][2][l31] + cbuf[cur][tsel][3][l31];
            const int t = t0 + 2 * q + tsel;
            scores[(size_t)l31 * T + t] = r;
            if (t < lenb) {                    // online (max, exp-sum) update
                const float m_new = fmaxf(m_run, r);
                s_run = s_run * __expf(m_run - m_new) + __expf(r - m_new);
                m_run = m_new;
            }
        }
    }

    // ---- fold tsel halves, one (M,S) per (b, block) ----
    if (mtile == 0 && lane < 32) { pm[tsel][l31] = m_run; ps[tsel][l31] = s_run; }
    __syncthreads();
    if (tid < 32) {
        const float m0 = pm[0][tid], m1 = pm[1][tid];
        const float s0 = ps[0][tid], s1 = ps[1][tid];
        const float M = fmaxf(m0, m1);
        const float S = s0 * __expf(m0 - M) + s1 * __expf(m1 - M);
        *(float2*)&part[((size_t)tid * 256 + blockIdx.x) * 2] = make_float2(M, S);
    }
}

// ---------------------------------------------------------------------------
// Kernel 3: wide softmax finish — fold 256 per-block partials per b, then
// rescale in place. 256 blocks (8 chunks x 32 b) x 256 threads x 4 elems.
// ---------------------------------------------------------------------------
__global__ __launch_bounds__(256) void k_sm_final(
    float* __restrict__ out,            // [B][T] raw scores -> probs
    const int* __restrict__ len_seq,
    const float* __restrict__ part)     // [B][256] x (M,S)
{
    const int b    = blockIdx.x >> 3;
    const int c    = blockIdx.x & 7;
    const int tid  = threadIdx.x;
    const int lane = tid & 63;
    const int wid  = tid >> 6;
    const int len  = len_seq[b];

    __shared__ float rm[4], rs[4];

    // thread tid owns partial blk=tid (coalesced float2 read)
    float2 p = *(const float2*)&part[((size_t)b * 256 + tid) * 2];
    float m = p.x, s = p.y;
#pragma unroll
    for (int off = 32; off >= 1; off >>= 1) {
        const float m2 = __shfl_xor(m, off);
        const float s2 = __shfl_xor(s, off);
        const float M = fmaxf(m, m2);
        s = s * __expf(m - M) + s2 * __expf(m2 - M);
        m = M;
    }
    if (lane == 0) { rm[wid] = m; rs[wid] = s; }
    __syncthreads();
    const float M = fmaxf(fmaxf(rm[0], rm[1]), fmaxf(rm[2], rm[3]));
    const float S = rs[0] * __expf(rm[0] - M) + rs[1] * __expf(rm[1] - M)
                  + rs[2] * __expf(rm[2] - M) + rs[3] * __expf(rm[3] - M);
    const float inv = 1.0f / S;

    float* srow = out + (size_t)b * T + c * 1024;
#pragma unroll
    for (int i = 0; i < 4; ++i) {
        const int tl = tid + i * 256;
        const int t  = c * 1024 + tl;
        const float x = srow[tl];
        srow[tl] = (t < len) ? __expf(x - M) * inv : 0.0f;
    }
}

// ---------------------------------------------------------------------------
extern "C" void kernel_launch(void* const* d_in, const int* in_sizes, int n_in,
                              void* d_out, int out_size, void* d_ws, size_t ws_size,
                              hipStream_t stream) {
    const float* hidden = (const float*)d_in[0];
    const float* enc    = (const float*)d_in[1];
    const int*   len    = (const int*)d_in[2];
    const float* W      = (const float*)d_in[3];
    const float* bb     = (const float*)d_in[4];
    const float* v      = (const float*)d_in[5];

    float* out  = (float*)d_out;
    float* u_ws = (float*)d_ws;                                     // 16 KB
    unsigned short* wpk = (unsigned short*)((char*)d_ws + WPK_OFF); // 64 KB
    float* part = (float*)((char*)d_ws + PART_OFF);                 // 64 KB

    k_prep<<<40, 256, 0, stream>>>(hidden, W, bb, u_ws, wpk);
    k_scores_mfma<<<256, 512, 0, stream>>>(enc, u_ws, v, wpk, len, out, part);
    k_sm_final<<<B * 8, 256, 0, stream>>>(out, len, part);
}

// Round 19
// 34.584 us; speedup vs baseline: 1.5683x; 1.0396x over previous
//
#include <hip/hip_runtime.h>
#include <hip/hip_bf16.h>

#define B 32
#define T 8192
#define H 128

typedef __attribute__((ext_vector_type(8)))  short short8_t;   // 8 bf16 = 4 VGPR
typedef __attribute__((ext_vector_type(16))) float f32x16;     // MFMA 32x32 acc

static __device__ __forceinline__ unsigned fbits(float x) { return __builtin_bit_cast(unsigned, x); }
static __device__ __forceinline__ float bfloat(unsigned u) { return __builtin_bit_cast(float, u); }

// pack float4 -> 2 u32 of bf16-hi (truncated). x-lo DROPPED (r17: precision
// budget -> LDS bandwidth; absmax 3.05e-5 vs 1.495e-4 threshold).
static __device__ __forceinline__ void pack4hi(const float4 f,
                                               unsigned& hi0, unsigned& hi1) {
    const unsigned u0 = fbits(f.x), u1 = fbits(f.y), u2 = fbits(f.z), u3 = fbits(f.w);
    hi0 = (u0 >> 16) | (u1 & 0xffff0000u);
    hi1 = (u2 >> 16) | (u3 & 0xffff0000u);
}

// ws layout: [0,16K) u fp32 ; [16K,80K) W2 hi|lo frags ; [80K,144K) sm partials
#define WPK_OFF  16384
#define PART_OFF 81920

// ---------------------------------------------------------------------------
// Kernel 1 (merged prep): blocks 0..31 -> u[b][h]; blocks 32..39 -> pack W2.
// ---------------------------------------------------------------------------
__global__ void k_prep(const float* __restrict__ hidden,
                       const float* __restrict__ W_attn,
                       const float* __restrict__ b_attn,
                       float* __restrict__ u,
                       unsigned short* __restrict__ wpk) {
    const int tid = threadIdx.x;
    if (blockIdx.x < 32) {
        const int b = blockIdx.x;
        __shared__ float hrow[H];
        if (tid < H) hrow[tid] = hidden[b * H + tid];
        __syncthreads();
        if (tid < H) {
            const float* w = W_attn + (size_t)tid * (2 * H);
            float acc = b_attn[tid];
#pragma unroll
            for (int k = 0; k < H; ++k) acc = fmaf(w[k], hrow[k], acc);
            u[b * H + tid] = acc;
        }
    } else {
        const int idx  = (blockIdx.x - 32) * 256 + tid;   // 0..2047
        const int s    = idx >> 8;
        const int m    = (idx >> 6) & 3;
        const int lane = idx & 63;
        const int h    = m * 32 + (lane & 31);
        const int k0   = s * 16 + (lane >> 5) * 8;
        const float* src = W_attn + (size_t)h * (2 * H) + H + k0;
        const int base = ((s * 4 + m) * 64 + lane) * 8;
#pragma unroll
        for (int e = 0; e < 8; ++e) {
            const float x = src[e];
            const unsigned ux = fbits(x);
            const unsigned hb = ux & 0xffff0000u;         // truncated bf16 hi
            const float r = x - bfloat(hb);               // exact remainder
            wpk[base + e]         = (unsigned short)(ux >> 16);
            wpk[16384 + base + e] = (unsigned short)(fbits(r) >> 16);
        }
    }
}

// ---------------------------------------------------------------------------
// Kernel 2: scores via MFMA — RAGGED-AWARE staging on the r17/r18 body.
//
// scores[b][t] is only consumed for t < len_seq[b] (E[sum len] ~ B*T/2):
//  (a) per-row stage guard: skip load+pack+LDS-write when the row's
//      t >= len[b]. Stale/uninit LDS only feeds MFMA COLUMN b (row b is
//      lane l31's own row -> column isolation), relu's fmaxf(NaN,0)=0
//      squashes garbage, online partial is t<len-guarded, k_sm_final
//      zeroes masked t. Valid-region math bit-identical.
//  (b) STRIDED tile assignment (tile = blk + 256*q): with contiguous
//      spans block 0 would keep full work (1 block/CU -> slowest block
//      sets the wall); striding gives every block an even mix of
//      low/high t so stage bytes shrink ~uniformly.
//
// Evidence ledger (unchanged): pre-pack at stage (r14 +22%), x-lo dropped
// (r17 +15%), hot loop = 1 ds_read_b128 + 2 MFMA /s-step, (512,2) +
// W2-in-regs (r15: (512,4) regresses), rotation swizzle (r9-r18), T14
// double-buffer (r11-r13 alternatives neutral), fused sm partials (r18).
// ---------------------------------------------------------------------------
__global__ __launch_bounds__(512, 2) void k_scores_mfma(
    const float* __restrict__ enc,                 // [T*B][H]
    const float* __restrict__ u,                   // [B][H]
    const float* __restrict__ v,                   // [H]
    const unsigned short* __restrict__ wpk,        // 64 KB frag-ordered hi|lo
    const int* __restrict__ len_seq,               // [B]
    float* __restrict__ scores,                    // [B][T]
    float* __restrict__ part)                      // [B][256] x (M,S)
{
    __shared__ uint2 hb[2][2048];                  // hi planes, 2 x 16 KB
    __shared__ float cbuf[2][2][4][32];            // [parity][tsel][mtile][b]
    __shared__ float pm[2][32], ps[2][32];         // partial fold buffers

    const int tid   = threadIdx.x;
    const int lane  = tid & 63;
    const int wid   = tid >> 6;     // 0..7
    const int tsel  = wid >> 2;     // 0..1 : which t of the tile
    const int mtile = wid & 3;      // 0..3 : 32-row h-tile
    const int l31   = lane & 31;
    const int kh    = lane >> 5;

    // staging role: 8 threads per tile-row, 4 float4 each
    const int srow = tid >> 3;      // tile row 0..63 (t-local = srow>>5, b = srow&31)
    const int st8  = tid & 7;

    const int blk = blockIdx.x;                 // strided tiles: tile(q) = blk + 256q
    const float4* enc4 = (const float4*)enc;    // 32 x 16B units per row

    // stage-guard constants: row's t for tile p = 2*(blk+256p) + (srow>>5)
    const int lenrow = len_seq[srow & 31];
    const int tsb    = 2 * blk + (srow >> 5);   // t of this row at p=0 (+512 per p)

    // ---- W2 fragments for this wave's mtile -> 64 VGPRs ----
    short8_t w2hi[8], w2lo[8];
#pragma unroll
    for (int s = 0; s < 8; ++s) {
        const int fo = ((s * 4 + mtile) * 64 + lane) * 8;   // ushort idx
        w2hi[s] = *(const short8_t*)(wpk + fo);
        w2lo[s] = *(const short8_t*)(wpk + 16384 + fo);
    }
    float4 uf[4], vv[4];
#pragma unroll
    for (int r4 = 0; r4 < 4; ++r4) {
        uf[r4] = *(const float4*)(u + l31 * H + mtile * 32 + r4 * 8 + kh * 4);
        vv[r4] = *(const float4*)(v + mtile * 32 + r4 * 8 + kh * 4);
    }
    const int lenb = len_seq[l31];              // used by flush threads

    // ---- prologue: tile 0 -> buf0 (guarded); issue tile-1 loads (guarded) ----
    float4 stg[4];
    {
        if (tsb < lenrow) {                     // tile 0 row valid
            const float4* gs = enc4 + ((size_t)(2 * blk) * 32 + srow) * 32;
#pragma unroll
            for (int i = 0; i < 4; ++i) stg[i] = gs[st8 + 8 * i];
#pragma unroll
            for (int i = 0; i < 4; ++i) {
                unsigned hi0, hi1;
                pack4hi(stg[i], hi0, hi1);
                const int p16 = st8 + 8 * i;
                const int idx = srow * 32 + (((p16 >> 1) + srow) & 15) * 2 + (p16 & 1);
                hb[0][idx] = make_uint2(hi0, hi1);
            }
        }
        if (tsb + 512 < lenrow) {               // tile 1 row valid
            const float4* gs1 = enc4 + ((size_t)(2 * (blk + 256)) * 32 + srow) * 32;
#pragma unroll
            for (int i = 0; i < 4; ++i) stg[i] = gs1[st8 + 8 * i];
        }
    }
    __syncthreads();   // buf0 ready

    const int rrow  = tsel * 32 + l31;          // reader's tile row
    const int rbase = rrow * 32;                // uint2 base of that row

    float m_run = -1e30f, s_run = 0.0f;         // online softmax partial

#pragma unroll 1
    for (int q = 0; q < 16; ++q) {
        const int cur = q & 1, nxt = cur ^ 1;

        // ---- pack+write tile q+1 (in stg) into buf[nxt]; guard matches the
        //      load guard that filled stg (same formula, p = q+1) ----
        if (q < 15 && tsb + 512 * (q + 1) < lenrow) {
#pragma unroll
            for (int i = 0; i < 4; ++i) {
                unsigned hi0, hi1;
                pack4hi(stg[i], hi0, hi1);
                const int p16 = st8 + 8 * i;
                const int idx = srow * 32 + (((p16 >> 1) + srow) & 15) * 2 + (p16 & 1);
                hb[nxt][idx] = make_uint2(hi0, hi1);
            }
        }
        // ---- issue tile q+2 loads (guarded; latency hides under compute) ----
        if (q < 14 && tsb + 512 * (q + 2) < lenrow) {
            const float4* gs = enc4 + ((size_t)(2 * (blk + 256 * (q + 2))) * 32 + srow) * 32;
#pragma unroll
            for (int i = 0; i < 4; ++i) stg[i] = gs[st8 + 8 * i];
        }

        // ---- compute own (t, mtile) from buf[cur]: 1 ds_read + 2 MFMA /s ----
        f32x16 acc;
#pragma unroll
        for (int r4 = 0; r4 < 4; ++r4) {
            acc[4 * r4 + 0] = uf[r4].x; acc[4 * r4 + 1] = uf[r4].y;
            acc[4 * r4 + 2] = uf[r4].z; acc[4 * r4 + 3] = uf[r4].w;
        }

#pragma unroll
        for (int s = 0; s < 8; ++s) {
            const int slot = (2 * s + kh + l31) & 15;       // (unit+row)&15
            const short8_t bh = *(const short8_t*)&hb[cur][rbase + slot * 2];
            acc = __builtin_amdgcn_mfma_f32_32x32x16_bf16(w2hi[s], bh, acc, 0, 0, 0);
            acc = __builtin_amdgcn_mfma_f32_32x32x16_bf16(w2lo[s], bh, acc, 0, 0, 0);
        }

        // ---- partial score over this wave's 32 h-rows ----
        float psum = 0.f;
#pragma unroll
        for (int r4 = 0; r4 < 4; ++r4) {
            psum = fmaf(fmaxf(acc[4 * r4 + 0], 0.f), vv[r4].x, psum);
            psum = fmaf(fmaxf(acc[4 * r4 + 1], 0.f), vv[r4].y, psum);
            psum = fmaf(fmaxf(acc[4 * r4 + 2], 0.f), vv[r4].z, psum);
            psum = fmaf(fmaxf(acc[4 * r4 + 3], 0.f), vv[r4].w, psum);
        }
        psum += __shfl_xor(psum, 32);   // collapse kh halves; lanes<32 hold b

        if (lane < 32) cbuf[cur][tsel][mtile][l31] = psum;

        __syncthreads();   // buf[nxt] written, cbuf[cur] visible, buf[cur] free

        if (mtile == 0 && lane < 32) {
            const float r = cbuf[cur][tsel][0][l31] + cbuf[cur][tsel][1][l31]
                          + cbuf[cur][tsel][2][l31] + cbuf[cur][tsel][3][l31];
            const int t = 2 * (blk + 256 * q) + tsel;
            scores[(size_t)l31 * T + t] = r;
            if (t < lenb) {                    // online (max, exp-sum) update
                const float m_new = fmaxf(m_run, r);
                s_run = s_run * __expf(m_run - m_new) + __expf(r - m_new);
                m_run = m_new;
            }
        }
    }

    // ---- fold tsel halves, one (M,S) per (b, block) ----
    if (mtile == 0 && lane < 32) { pm[tsel][l31] = m_run; ps[tsel][l31] = s_run; }
    __syncthreads();
    if (tid < 32) {
        const float m0 = pm[0][tid], m1 = pm[1][tid];
        const float s0 = ps[0][tid], s1 = ps[1][tid];
        const float M = fmaxf(m0, m1);
        const float S = s0 * __expf(m0 - M) + s1 * __expf(m1 - M);
        *(float2*)&part[((size_t)tid * 256 + blk) * 2] = make_float2(M, S);
    }
}

// ---------------------------------------------------------------------------
// Kernel 3: wide softmax finish — fold 256 per-block partials per b, then
// rescale in place. 256 blocks (8 chunks x 32 b) x 256 threads x 4 elems.
// ---------------------------------------------------------------------------
__global__ __launch_bounds__(256) void k_sm_final(
    float* __restrict__ out,            // [B][T] raw scores -> probs
    const int* __restrict__ len_seq,
    const float* __restrict__ part)     // [B][256] x (M,S)
{
    const int b    = blockIdx.x >> 3;
    const int c    = blockIdx.x & 7;
    const int tid  = threadIdx.x;
    const int lane = tid & 63;
    const int wid  = tid >> 6;
    const int len  = len_seq[b];

    __shared__ float rm[4], rs[4];

    float2 p = *(const float2*)&part[((size_t)b * 256 + tid) * 2];
    float m = p.x, s = p.y;
#pragma unroll
    for (int off = 32; off >= 1; off >>= 1) {
        const float m2 = __shfl_xor(m, off);
        const float s2 = __shfl_xor(s, off);
        const float M = fmaxf(m, m2);
        s = s * __expf(m - M) + s2 * __expf(m2 - M);
        m = M;
    }
    if (lane == 0) { rm[wid] = m; rs[wid] = s; }
    __syncthreads();
    const float M = fmaxf(fmaxf(rm[0], rm[1]), fmaxf(rm[2], rm[3]));
    const float S = rs[0] * __expf(rm[0] - M) + rs[1] * __expf(rm[1] - M)
                  + rs[2] * __expf(rm[2] - M) + rs[3] * __expf(rm[3] - M);
    const float inv = 1.0f / S;

    float* srow = out + (size_t)b * T + c * 1024;
#pragma unroll
    for (int i = 0; i < 4; ++i) {
        const int tl = tid + i * 256;
        const int t  = c * 1024 + tl;
        const float x = srow[tl];
        srow[tl] = (t < len) ? __expf(x - M) * inv : 0.0f;
    }
}

// ---------------------------------------------------------------------------
extern "C" void kernel_launch(void* const* d_in, const int* in_sizes, int n_in,
                              void* d_out, int out_size, void* d_ws, size_t ws_size,
                              hipStream_t stream) {
    const float* hidden = (const float*)d_in[0];
    const float* enc    = (const float*)d_in[1];
    const int*   len    = (const int*)d_in[2];
    const float* W      = (const float*)d_in[3];
    const float* bb     = (const float*)d_in[4];
    const float* v      = (const float*)d_in[5];

    float* out  = (float*)d_out;
    float* u_ws = (float*)d_ws;                                     // 16 KB
    unsigned short* wpk = (unsigned short*)((char*)d_ws + WPK_OFF); // 64 KB
    float* part = (float*)((char*)d_ws + PART_OFF);                 // 64 KB

    k_prep<<<40, 256, 0, stream>>>(hidden, W, bb, u_ws, wpk);
    k_scores_mfma<<<256, 512, 0, stream>>>(enc, u_ws, v, wpk, len, out, part);
    k_sm_final<<<B * 8, 256, 0, stream>>>(out, len, part);
}